// Round 1
// baseline (504.370 us; speedup 1.0000x reference)
//
#include <hip/hip_runtime.h>
#include <math.h>

#define N 4096
#define D 512
#define NUM_STEPS 151
#define HALF_BINS 75
#define INV_STEP 75.0f
#define P_TOTAL 8386560.0f   // N*(N-1)/2, exact in fp32 (< 2^24)

// ws layout (float/int indices into d_ws)
#define WS_SUM_ALL 0
#define WS_POS_CNT 1          // int
#define WS_SUM_POS 2
#define WS_S_POS   3
#define WS_G_OFF   8          // 151 floats
#define WS_LIST_OFF 1024
#define MAXP (1 << 18)        // 262144-entry pos-sim list (expect ~11K)
#define WS_FEAT_OFF (WS_LIST_OFF + MAXP)   // 4096x512 fp32 normalized feats

// ---------------- K1: row L2-normalize ----------------
__global__ __launch_bounds__(256) void k_normalize(const float* __restrict__ feat,
                                                   float* __restrict__ nf) {
    int row = blockIdx.x;
    int t = threadIdx.x;
    const float* fr = feat + (size_t)row * D;
    float a = fr[t];
    float b = fr[t + 256];
    float ss = a * a + b * b;
    for (int o = 32; o > 0; o >>= 1) ss += __shfl_down(ss, o, 64);
    __shared__ float wsum[4];
    int lane = t & 63, wid = t >> 6;
    if (lane == 0) wsum[wid] = ss;
    __syncthreads();
    float tot = wsum[0] + wsum[1] + wsum[2] + wsum[3];
    float inv = 1.0f / sqrtf(tot);
    nf[(size_t)row * D + t] = a * inv;
    nf[(size_t)row * D + t + 256] = b * inv;
}

// ---------------- K2: pos-pair similarities (same-class only) ----------------
__global__ __launch_bounds__(256) void k_pospairs(const float* __restrict__ nf,
                                                  const int* __restrict__ cls,
                                                  float* __restrict__ posS,
                                                  int* __restrict__ posCnt) {
    int i = blockIdx.x;
    int ci = cls[i];
    __shared__ __align__(16) float rowi[D];
    for (int k = threadIdx.x; k < D; k += 256) rowi[k] = nf[(size_t)i * D + k];
    __syncthreads();
    const float4* a4 = (const float4*)rowi;
    for (int j = i + 1 + (int)threadIdx.x; j < N; j += 256) {
        if (cls[j] == ci) {
            const float4* r4 = (const float4*)(nf + (size_t)j * D);
            float s = 0.f;
            #pragma unroll 8
            for (int k = 0; k < D / 4; ++k) {
                float4 x = a4[k], y = r4[k];
                s += x.x * y.x + x.y * y.y + x.z * y.z + x.w * y.w;
            }
            int idx = atomicAdd(posCnt, 1);
            if (idx < MAXP) posS[idx] = s;
        }
    }
}

// ---------------- K3: hist_pos -> cdf -> G table, plus sum_pos g ----------------
__global__ __launch_bounds__(256) void k_build_cdf(const float* __restrict__ posS,
                                                   const int* __restrict__ posCnt,
                                                   float* __restrict__ G,
                                                   float* __restrict__ sumPosOut,
                                                   float* __restrict__ sPosOut) {
    __shared__ float hist[NUM_STEPS];
    __shared__ float Gs[NUM_STEPS];
    int t = threadIdx.x;
    int C = *posCnt;
    if (C > MAXP) C = MAXP;
    for (int b = t; b < NUM_STEPS; b += 256) hist[b] = 0.f;
    __syncthreads();
    for (int p = t; p < C; p += 256) {
        float s = posS[p];
        float x = s * INV_STEP;
        float kf = floorf(x);
        float frac = x - kf;
        int kI = (int)kf;
        int lo = min(max(kI + HALF_BINS, 0), NUM_STEPS - 1);
        int hi = min(max(kI + HALF_BINS + 1, 0), NUM_STEPS - 1);
        atomicAdd(&hist[lo], 1.0f - frac);
        atomicAdd(&hist[hi], frac);
    }
    __syncthreads();
    if (t == 0) {
        float invC = (C > 0) ? (1.0f / (float)C) : 0.f;
        float acc = 0.f;
        for (int b = 0; b < NUM_STEPS; ++b) {
            acc += hist[b];
            Gs[b] = acc * invC;
        }
    }
    __syncthreads();
    for (int b = t; b < NUM_STEPS; b += 256) G[b] = Gs[b];
    float ps = 0.f;
    for (int p = t; p < C; p += 256) {
        float s = posS[p];
        float x = s * INV_STEP;
        float kf = floorf(x);
        float frac = x - kf;
        int kI = (int)kf;
        int lo = min(max(kI + HALF_BINS, 0), NUM_STEPS - 1);
        int hi = min(max(kI + HALF_BINS + 1, 0), NUM_STEPS - 1);
        ps += (1.f - frac) * Gs[lo] + frac * Gs[hi];
    }
    for (int o = 32; o > 0; o >>= 1) ps += __shfl_down(ps, o, 64);
    __shared__ float wsum[4];
    int lane = t & 63, wid = t >> 6;
    if (lane == 0) wsum[wid] = ps;
    __syncthreads();
    if (t == 0) {
        *sumPosOut = wsum[0] + wsum[1] + wsum[2] + wsum[3];
        *sPosOut = (float)C;
    }
}

// ---------------- K4: upper-tri tiled Gram + g-lookup accumulate ----------------
__global__ __launch_bounds__(256) void k_main(const float* __restrict__ nf,
                                              const float* __restrict__ G,
                                              float* __restrict__ sumAll) {
    int ti = blockIdx.x, tj = blockIdx.y;
    if (tj < ti) return;

    __shared__ float As[16][65];
    __shared__ float Bs[16][65];
    __shared__ float Gs[NUM_STEPS];

    int tid = threadIdx.x;
    for (int b = tid; b < NUM_STEPS; b += 256) Gs[b] = G[b];

    int tx = tid & 15, ty = tid >> 4;
    int rowA = ti * 64, rowB = tj * 64;

    float acc[4][4] = {};

    int kk = tid & 15;   // k within BK
    int rr = tid >> 4;   // base row within tile

    for (int kb = 0; kb < D / 16; ++kb) {
        #pragma unroll
        for (int q = 0; q < 4; ++q) {
            int r = rr + 16 * q;
            As[kk][r] = nf[(size_t)(rowA + r) * D + kb * 16 + kk];
            Bs[kk][r] = nf[(size_t)(rowB + r) * D + kb * 16 + kk];
        }
        __syncthreads();
        #pragma unroll
        for (int k2 = 0; k2 < 16; ++k2) {
            float av[4], bv[4];
            #pragma unroll
            for (int r = 0; r < 4; ++r) av[r] = As[k2][ty * 4 + r];
            #pragma unroll
            for (int c = 0; c < 4; ++c) bv[c] = Bs[k2][tx * 4 + c];
            #pragma unroll
            for (int r = 0; r < 4; ++r)
                #pragma unroll
                for (int c = 0; c < 4; ++c)
                    acc[r][c] += av[r] * bv[c];
        }
        __syncthreads();
    }

    // epilogue: g(s) lookup, upper-triangle mask
    float gsum = 0.f;
    #pragma unroll
    for (int r = 0; r < 4; ++r) {
        int gi = rowA + ty * 4 + r;
        #pragma unroll
        for (int c = 0; c < 4; ++c) {
            int gj = rowB + tx * 4 + c;
            if (gi < gj) {
                float s = acc[r][c];
                float x = s * INV_STEP;
                float kf = floorf(x);
                float frac = x - kf;
                int kI = (int)kf;
                int lo = min(max(kI + HALF_BINS, 0), NUM_STEPS - 1);
                int hi = min(max(kI + HALF_BINS + 1, 0), NUM_STEPS - 1);
                gsum += (1.f - frac) * Gs[lo] + frac * Gs[hi];
            }
        }
    }
    for (int o = 32; o > 0; o >>= 1) gsum += __shfl_down(gsum, o, 64);
    __shared__ float wsum[4];
    if ((tid & 63) == 0) wsum[tid >> 6] = gsum;
    __syncthreads();
    if (tid == 0) atomicAdd(sumAll, wsum[0] + wsum[1] + wsum[2] + wsum[3]);
}

// ---------------- K5: final combine ----------------
__global__ void k_final(const float* __restrict__ wsf, float* __restrict__ out) {
    float C = wsf[WS_S_POS];
    float sneg = P_TOTAL - C;
    out[0] = (wsf[WS_SUM_ALL] - wsf[WS_SUM_POS]) / sneg;
}

extern "C" void kernel_launch(void* const* d_in, const int* in_sizes, int n_in,
                              void* d_out, int out_size, void* d_ws, size_t ws_size,
                              hipStream_t stream) {
    const float* feat = (const float*)d_in[0];
    const int* cls = (const int*)d_in[1];
    float* out = (float*)d_out;
    float* wsf = (float*)d_ws;
    int* wsi = (int*)d_ws;

    // zero the accumulator / counter / G header region
    hipMemsetAsync(d_ws, 0, 4096, stream);

    float* nf = wsf + WS_FEAT_OFF;
    float* posS = wsf + WS_LIST_OFF;
    float* G = wsf + WS_G_OFF;

    k_normalize<<<N, 256, 0, stream>>>(feat, nf);
    k_pospairs<<<N, 256, 0, stream>>>(nf, cls, posS, wsi + WS_POS_CNT);
    k_build_cdf<<<1, 256, 0, stream>>>(posS, wsi + WS_POS_CNT, G,
                                       wsf + WS_SUM_POS, wsf + WS_S_POS);
    dim3 grid(64, 64);
    k_main<<<grid, 256, 0, stream>>>(nf, G, wsf + WS_SUM_ALL);
    k_final<<<1, 1, 0, stream>>>(wsf, out);
}

// Round 2
// 274.564 us; speedup vs baseline: 1.8370x; 1.8370x over previous
//
#include <hip/hip_runtime.h>
#include <math.h>

#define N 4096
#define D 512
#define NUM_STEPS 151
#define HALF_BINS 75
#define INV_STEP 75.0f
#define P_TOTAL 8386560.0f   // N*(N-1)/2, exact in fp32 (< 2^24)

// ws layout (float indices into d_ws)
#define WS_SUM_ALL 0
#define WS_POS_CNT 1          // int
#define WS_SUM_POS 2
#define WS_S_POS   3
#define WS_G_OFF   8          // 151 floats
#define WS_LIST_OFF 1024
#define MAXP (1 << 18)        // 262144-entry pos-sim list (expect ~11K)
#define WS_FEAT_OFF (WS_LIST_OFF + MAXP)          // 4096x512 fp32 normalized feats
#define WS_FEATB_OFF (WS_FEAT_OFF + N * D)        // 4096x512 bf16 normalized feats (as 1M floats)

typedef __bf16 bf16x8 __attribute__((ext_vector_type(8)));
typedef float floatx4 __attribute__((ext_vector_type(4)));

// ---------------- K1: row L2-normalize (fp32 + bf16 outputs) ----------------
__global__ __launch_bounds__(256) void k_normalize(const float* __restrict__ feat,
                                                   float* __restrict__ nf,
                                                   __bf16* __restrict__ nfb) {
    int row = blockIdx.x;
    int t = threadIdx.x;
    const float* fr = feat + (size_t)row * D;
    float a = fr[t];
    float b = fr[t + 256];
    float ss = a * a + b * b;
    for (int o = 32; o > 0; o >>= 1) ss += __shfl_down(ss, o, 64);
    __shared__ float wsum[4];
    int lane = t & 63, wid = t >> 6;
    if (lane == 0) wsum[wid] = ss;
    __syncthreads();
    float tot = wsum[0] + wsum[1] + wsum[2] + wsum[3];
    float inv = 1.0f / sqrtf(tot);
    float na = a * inv, nb = b * inv;
    nf[(size_t)row * D + t] = na;
    nf[(size_t)row * D + t + 256] = nb;
    nfb[(size_t)row * D + t] = (__bf16)na;
    nfb[(size_t)row * D + t + 256] = (__bf16)nb;
}

// ---------------- K2: pos-pair similarities (same-class only, fp32) ----------------
__global__ __launch_bounds__(256) void k_pospairs(const float* __restrict__ nf,
                                                  const int* __restrict__ cls,
                                                  float* __restrict__ posS,
                                                  int* __restrict__ posCnt) {
    int i = blockIdx.x;
    int ci = cls[i];
    __shared__ __align__(16) float rowi[D];
    for (int k = threadIdx.x; k < D; k += 256) rowi[k] = nf[(size_t)i * D + k];
    __syncthreads();
    const float4* a4 = (const float4*)rowi;
    for (int j = i + 1 + (int)threadIdx.x; j < N; j += 256) {
        if (cls[j] == ci) {
            const float4* r4 = (const float4*)(nf + (size_t)j * D);
            float s = 0.f;
            #pragma unroll 8
            for (int k = 0; k < D / 4; ++k) {
                float4 x = a4[k], y = r4[k];
                s += x.x * y.x + x.y * y.y + x.z * y.z + x.w * y.w;
            }
            int idx = atomicAdd(posCnt, 1);
            if (idx < MAXP) posS[idx] = s;
        }
    }
}

// ---------------- K3: hist_pos -> cdf -> G table, plus sum_pos g ----------------
__global__ __launch_bounds__(256) void k_build_cdf(const float* __restrict__ posS,
                                                   const int* __restrict__ posCnt,
                                                   float* __restrict__ G,
                                                   float* __restrict__ sumPosOut,
                                                   float* __restrict__ sPosOut) {
    __shared__ float hist[NUM_STEPS];
    __shared__ float Gs[NUM_STEPS];
    int t = threadIdx.x;
    int C = *posCnt;
    if (C > MAXP) C = MAXP;
    for (int b = t; b < NUM_STEPS; b += 256) hist[b] = 0.f;
    __syncthreads();
    for (int p = t; p < C; p += 256) {
        float s = posS[p];
        float x = s * INV_STEP;
        float kf = floorf(x);
        float frac = x - kf;
        int kI = (int)kf;
        int lo = min(max(kI + HALF_BINS, 0), NUM_STEPS - 1);
        int hi = min(max(kI + HALF_BINS + 1, 0), NUM_STEPS - 1);
        atomicAdd(&hist[lo], 1.0f - frac);
        atomicAdd(&hist[hi], frac);
    }
    __syncthreads();
    if (t == 0) {
        float invC = (C > 0) ? (1.0f / (float)C) : 0.f;
        float acc = 0.f;
        for (int b = 0; b < NUM_STEPS; ++b) {
            acc += hist[b];
            Gs[b] = acc * invC;
        }
    }
    __syncthreads();
    for (int b = t; b < NUM_STEPS; b += 256) G[b] = Gs[b];
    float ps = 0.f;
    for (int p = t; p < C; p += 256) {
        float s = posS[p];
        float x = s * INV_STEP;
        float kf = floorf(x);
        float frac = x - kf;
        int kI = (int)kf;
        int lo = min(max(kI + HALF_BINS, 0), NUM_STEPS - 1);
        int hi = min(max(kI + HALF_BINS + 1, 0), NUM_STEPS - 1);
        ps += (1.f - frac) * Gs[lo] + frac * Gs[hi];
    }
    for (int o = 32; o > 0; o >>= 1) ps += __shfl_down(ps, o, 64);
    __shared__ float wsum[4];
    int lane = t & 63, wid = t >> 6;
    if (lane == 0) wsum[wid] = ps;
    __syncthreads();
    if (t == 0) {
        *sumPosOut = wsum[0] + wsum[1] + wsum[2] + wsum[3];
        *sPosOut = (float)C;
    }
}

// ---------------- K4: upper-tri 128x128 MFMA Gram + g-lookup accumulate ----------------
#define TILES_1D 32            // 4096 / 128
#define LDSS 40                // LDS row stride in bf16 (32 + 8 pad; 80B, 2-way bank alias = free)

__global__ __launch_bounds__(256) void k_gram(const __bf16* __restrict__ nfb,
                                              const float* __restrict__ G,
                                              float* __restrict__ sumAll) {
    // map linear block id -> upper-tri tile (ti, tj), tj >= ti
    int bid = blockIdx.x;
    int ti = 0, rem = bid;
    while (rem >= TILES_1D - ti) { rem -= TILES_1D - ti; ++ti; }
    int tj = ti + rem;

    __shared__ __align__(16) __bf16 As[128 * LDSS];
    __shared__ __align__(16) __bf16 Bs[128 * LDSS];
    __shared__ float Gs[NUM_STEPS];

    int tid = threadIdx.x;
    for (int b = tid; b < NUM_STEPS; b += 256) Gs[b] = G[b];

    int lane = tid & 63;
    int wave = tid >> 6;
    int wm = (wave >> 1) * 64;   // wave's 64-row region in A
    int wn = (wave & 1) * 64;    // wave's 64-row region in B
    int fr = lane & 15;          // row within 16 (A-row / B-row)
    int fk = (lane >> 4) * 8;    // k offset within BK

    int rowA0 = ti * 128, rowB0 = tj * 128;

    floatx4 acc[4][4] = {};

    // staging decomposition: 2 chunks of 8 bf16 per thread per matrix
    int e0 = tid * 8;            // chunk 0 element index (of 4096)
    int e1 = e0 + 2048;          // chunk 1
    int r0 = e0 >> 5, c0 = e0 & 31;
    int r1 = e1 >> 5, c1 = e1 & 31;

    for (int kb = 0; kb < D / 32; ++kb) {
        int kbase = kb * 32;
        // stage A and B tiles: 128 rows x 32 bf16, 16B vector loads
        *(float4*)(&As[r0 * LDSS + c0]) = *(const float4*)(nfb + (size_t)(rowA0 + r0) * D + kbase + c0);
        *(float4*)(&As[r1 * LDSS + c1]) = *(const float4*)(nfb + (size_t)(rowA0 + r1) * D + kbase + c1);
        *(float4*)(&Bs[r0 * LDSS + c0]) = *(const float4*)(nfb + (size_t)(rowB0 + r0) * D + kbase + c0);
        *(float4*)(&Bs[r1 * LDSS + c1]) = *(const float4*)(nfb + (size_t)(rowB0 + r1) * D + kbase + c1);
        __syncthreads();

        bf16x8 a[4], b[4];
        #pragma unroll
        for (int r = 0; r < 4; ++r)
            a[r] = *(const bf16x8*)(&As[(wm + r * 16 + fr) * LDSS + fk]);
        #pragma unroll
        for (int c = 0; c < 4; ++c)
            b[c] = *(const bf16x8*)(&Bs[(wn + c * 16 + fr) * LDSS + fk]);

        #pragma unroll
        for (int r = 0; r < 4; ++r)
            #pragma unroll
            for (int c = 0; c < 4; ++c)
                acc[r][c] = __builtin_amdgcn_mfma_f32_16x16x32_bf16(a[r], b[c], acc[r][c], 0, 0, 0);
        __syncthreads();
    }

    // epilogue: g(s) lookup with upper-triangle mask
    // C/D layout (16x16x32): col = lane&15 (B index), row = (lane>>4)*4 + reg (A index)
    int crow = (lane >> 4) * 4;
    int ccol = lane & 15;
    float gsum = 0.f;
    #pragma unroll
    for (int r = 0; r < 4; ++r) {
        #pragma unroll
        for (int c = 0; c < 4; ++c) {
            #pragma unroll
            for (int reg = 0; reg < 4; ++reg) {
                int gi = rowA0 + wm + r * 16 + crow + reg;
                int gj = rowB0 + wn + c * 16 + ccol;
                if (gi < gj) {
                    float s = acc[r][c][reg];
                    float x = s * INV_STEP;
                    float kf = floorf(x);
                    float frac = x - kf;
                    int kI = (int)kf;
                    int lo = min(max(kI + HALF_BINS, 0), NUM_STEPS - 1);
                    int hi = min(max(kI + HALF_BINS + 1, 0), NUM_STEPS - 1);
                    gsum += (1.f - frac) * Gs[lo] + frac * Gs[hi];
                }
            }
        }
    }
    for (int o = 32; o > 0; o >>= 1) gsum += __shfl_down(gsum, o, 64);
    __shared__ float wsum[4];
    if ((tid & 63) == 0) wsum[tid >> 6] = gsum;
    __syncthreads();
    if (tid == 0) atomicAdd(sumAll, wsum[0] + wsum[1] + wsum[2] + wsum[3]);
}

// ---------------- K5: final combine ----------------
__global__ void k_final(const float* __restrict__ wsf, float* __restrict__ out) {
    float C = wsf[WS_S_POS];
    float sneg = P_TOTAL - C;
    out[0] = (wsf[WS_SUM_ALL] - wsf[WS_SUM_POS]) / sneg;
}

extern "C" void kernel_launch(void* const* d_in, const int* in_sizes, int n_in,
                              void* d_out, int out_size, void* d_ws, size_t ws_size,
                              hipStream_t stream) {
    const float* feat = (const float*)d_in[0];
    const int* cls = (const int*)d_in[1];
    float* out = (float*)d_out;
    float* wsf = (float*)d_ws;
    int* wsi = (int*)d_ws;

    // zero the accumulator / counter / G header region
    hipMemsetAsync(d_ws, 0, 4096, stream);

    float* nf = wsf + WS_FEAT_OFF;
    __bf16* nfb = (__bf16*)(wsf + WS_FEATB_OFF);
    float* posS = wsf + WS_LIST_OFF;
    float* G = wsf + WS_G_OFF;

    k_normalize<<<N, 256, 0, stream>>>(feat, nf, nfb);
    k_pospairs<<<N, 256, 0, stream>>>(nf, cls, posS, wsi + WS_POS_CNT);
    k_build_cdf<<<1, 256, 0, stream>>>(posS, wsi + WS_POS_CNT, G,
                                       wsf + WS_SUM_POS, wsf + WS_S_POS);
    int nTiles = TILES_1D * (TILES_1D + 1) / 2;   // 528 upper-tri 128x128 tiles
    k_gram<<<nTiles, 256, 0, stream>>>(nfb, G, wsf + WS_SUM_ALL);
    k_final<<<1, 1, 0, stream>>>(wsf, out);
}